// Round 6
// baseline (481.237 us; speedup 1.0000x reference)
//
#include <hip/hip_runtime.h>

#define T_STEPS 256
#define FEAT 16
#define U1 24
#define U2 48
#define SLOTS 8
#define ROWB 144                       // ring row stride (16B-aligned, known conflicts)
#define SLOT_B (16 * ROWB + 128)       // 16 rows + 16 x float2 (mu, rs)
#define SUMS_OFF (16 * ROWB)

typedef short bf16x8 __attribute__((ext_vector_type(8)));
typedef float f32x4 __attribute__((ext_vector_type(4)));

__device__ __forceinline__ unsigned short f2bf(float f) {
    unsigned u = __float_as_uint(f);
    u += 0x7fffu + ((u >> 16) & 1u);   // RNE
    return (unsigned short)(u >> 16);
}

#if defined(__has_builtin)
#if __has_builtin(__builtin_amdgcn_cvt_pk_bf16_f32)
#define HAVE_PKBF16 1
#endif
#endif

__device__ __forceinline__ unsigned pk2(float a, float b) {
#ifdef HAVE_PKBF16
    typedef __bf16 bf2 __attribute__((ext_vector_type(2)));
    union { bf2 v; unsigned u; } cv;
    cv.v = __builtin_amdgcn_cvt_pk_bf16_f32(a, b);       // lo = a, hi = b, RNE
    return cv.u;
#else
    unsigned ua = __float_as_uint(a), ub = __float_as_uint(b);
    ua += 0x7fffu + ((ua >> 16) & 1u);
    ub += 0x7fffu + ((ub >> 16) & 1u);
    return __builtin_amdgcn_perm(ub, ua, 0x07060302);    // [b.hi16 | a.hi16]
#endif
}
__device__ __forceinline__ float bfr(float x) {          // f32 -> bf16 -> f32
    return __uint_as_float(((unsigned)f2bf(x)) << 16);
}
__device__ __forceinline__ float fast_tanh(float z) {
    return 1.0f - 2.0f / (1.0f + __expf(2.0f * z));      // robust at +/-inf
}
__device__ __forceinline__ unsigned bpermu(int addr, unsigned v) {
    return (unsigned)__builtin_amdgcn_ds_bpermute(addr, (int)v);
}

union FragU { bf16x8 v; unsigned u[4]; };

#define MFMA(A, B, C) __builtin_amdgcn_mfma_f32_16x16x32_bf16((A), (B), (C), 0, 0, 0)

// lgkm-only barrier (0xC07F = vmcnt(63) expcnt(7) lgkmcnt(0)):
// input-prefetch global loads stay in flight across the barrier.
__device__ __forceinline__ void bar_sync() {
    asm volatile("" ::: "memory");
    __builtin_amdgcn_s_waitcnt(0xC07F);
    __builtin_amdgcn_s_barrier();
    asm volatile("" ::: "memory");
}

__global__ __launch_bounds__(128) void rnn_kernel(
    const float* __restrict__ seq,
    const float* __restrict__ W1, const float* __restrict__ b1,
    const float* __restrict__ Wr1, const float* __restrict__ br1,
    const float* __restrict__ g1, const float* __restrict__ be1,
    const float* __restrict__ W2, const float* __restrict__ b2,
    const float* __restrict__ Wr2, const float* __restrict__ br2,
    const float* __restrict__ g2, const float* __restrict__ be2,
    const float* __restrict__ Wout, const float* __restrict__ bout,
    float* __restrict__ out)
{
    __shared__ __align__(16) unsigned char ring[SLOTS * SLOT_B];   // n1 rows + (mu,rs)

    const int tid = threadIdx.x;
    const int w = tid >> 6;              // 0 = layer-1 producer, 1 = layer-2 consumer
    const int lane = tid & 63;
    const int j15 = lane & 15;
    const int g = lane >> 4;
    const bool lo = (g < 2);
    const f32x4 z4 = {0.f, 0.f, 0.f, 0.f};

    // bpermute byte-addresses for C-layout -> frag dword exchange (wave-relative)
    const int aA = (j15 + 16 * (2 * (g & 1))) << 2;
    const int aB = aA + 64;              // +16 lanes

    if (w == 0) {
        // ================= PRODUCER: layer 1 (s1 chain) =================
        bf16x8 A1[2], A2[2];
#pragma unroll
        for (int t = 0; t < 2; ++t) {
            const int m = 16 * t + j15;
            FragU f1, f2;
#pragma unroll
            for (int j = 0; j < 8; ++j) {
                const int k = 8 * g + j;
                float v1 = 0.f, v2 = 0.f;
                if (m < U1) {
                    if (k < FEAT) v1 = W1[k * U1 + m];
                    else if (k == FEAT) v1 = b1[m];      // bias col (input k16 == 1)
                    if (k < U1) v2 = Wr1[k * U1 + m];
                    else if (k == U1) v2 = br1[m];       // bias col (x24 == 1)
                } else if (m == U1 && k == FEAT) {
                    v1 = 1.f;                            // keeps x24 = 1 each step
                }
                f1.v[j] = (short)f2bf(v1);
                f2.v[j] = (short)f2bf(v2);
            }
            A1[t] = f1.v; A2[t] = f2.v;
        }
        const unsigned cdw0 = (g == 2) ? 0x00003F80u : 0u;   // input k16 = 1.0

        const float* sp = seq + (size_t)(blockIdx.x * 16 + j15) * (T_STEPS * FEAT) + 8 * g;
        const bool ld = (lane < 32);

        f32x4 s1[2] = {z4, z4};

        auto pstep = [&](int t, const float4 ca, const float4 cb) {
            FragU inf;
            const unsigned p0 = pk2(ca.x, ca.y), p1 = pk2(ca.z, ca.w);
            const unsigned p2 = pk2(cb.x, cb.y), p3 = pk2(cb.z, cb.w);
            inf.u[0] = lo ? p0 : cdw0;
            inf.u[1] = lo ? p1 : 0u;
            inf.u[2] = lo ? p2 : 0u;
            inf.u[3] = lo ? p3 : 0u;

            // GEMM1: x^T = [W1^T|b1].in^T + s1  (C-layout)
            const f32x4 x0 = MFMA(A1[0], inf.v, s1[0]);
            const f32x4 x1 = MFMA(A1[1], inf.v, s1[1]);

            // C-layout -> B-frag via register bpermute exchange (no LDS RT)
            const unsigned px00 = pk2(x0[0], x0[1]), px01 = pk2(x0[2], x0[3]);
            const unsigned px10 = pk2(x1[0], x1[1]), px11 = pk2(x1[2], x1[3]);
            const unsigned r00 = bpermu(aA, px00), r01 = bpermu(aA, px01);
            const unsigned r02 = bpermu(aB, px00), r03 = bpermu(aB, px01);
            const unsigned r10 = bpermu(aA, px10), r11 = bpermu(aA, px11);
            const unsigned r12 = bpermu(aB, px10), r13 = bpermu(aB, px11);
            FragU xf;
            xf.u[0] = lo ? r00 : r10;
            xf.u[1] = lo ? r01 : r11;
            xf.u[2] = lo ? r02 : r12;
            xf.u[3] = lo ? r03 : r13;

            // GEMM2: ns1 = tanh([Wr1^T|br1].x^T)
            const f32x4 d0 = MFMA(A2[0], xf.v, z4);
            const f32x4 d1 = MFMA(A2[1], xf.v, z4);
            float n1a[4], n1b[4];
#pragma unroll
            for (int r = 0; r < 4; ++r) {
                n1a[r] = fast_tanh(d0[r]); n1b[r] = fast_tanh(d1[r]);
                s1[0][r] = n1a[r];         s1[1][r] = n1b[r];
            }

            // ring: transposed n1 rows (rows 24..31 are exact zeros)
            unsigned char* rp = ring + (size_t)(t & (SLOTS - 1)) * SLOT_B + (size_t)j15 * ROWB;
            *(uint2*)(rp + 8 * g)      = make_uint2(pk2(n1a[0], n1a[1]), pk2(n1a[2], n1a[3]));
            *(uint2*)(rp + 32 + 8 * g) = make_uint2(pk2(n1b[0], n1b[1]), pk2(n1b[2], n1b[3]));

            // LN stats off-chain: mu, rs from f32 n1 (xor16/32 reduce over g-lanes)
            float sm = 0.f, sq = 0.f;
#pragma unroll
            for (int r = 0; r < 4; ++r) {
                sm += n1a[r] + n1b[r];
                sq = fmaf(n1a[r], n1a[r], sq);
                sq = fmaf(n1b[r], n1b[r], sq);
            }
            sm += __shfl_xor(sm, 16, 64); sq += __shfl_xor(sq, 16, 64);
            sm += __shfl_xor(sm, 32, 64); sq += __shfl_xor(sq, 32, 64);
            const float mu = sm * (1.f / U1);
            const float rs = rsqrtf(sq * (1.f / U1) - mu * mu + 1e-3f);
            if (lane < 16)
                *(float2*)(ring + (size_t)(t & (SLOTS - 1)) * SLOT_B + SUMS_OFF + 8 * j15) =
                    make_float2(mu, rs);
        };

        // load macro 0
        float4 ca[4], cb[4], na[4], nb[4];
        if (ld) {
#pragma unroll
            for (int i = 0; i < 4; ++i) {
                ca[i] = *(const float4*)(sp + i * 16);
                cb[i] = *(const float4*)(sp + i * 16 + 4);
            }
        }
#pragma unroll 1
        for (int j = 0; j < 64; ++j) {
            const int jn = (j + 1 < 64) ? j + 1 : j;     // prefetch next macro
            if (ld) {
#pragma unroll
                for (int i = 0; i < 4; ++i) {
                    na[i] = *(const float4*)(sp + (4 * jn + i) * 16);
                    nb[i] = *(const float4*)(sp + (4 * jn + i) * 16 + 4);
                }
            }
#pragma unroll
            for (int i = 0; i < 4; ++i) pstep(4 * j + i, ca[i], cb[i]);
            bar_sync();                                   // 64 in-loop barriers
#pragma unroll
            for (int i = 0; i < 4; ++i) { ca[i] = na[i]; cb[i] = nb[i]; }
        }
        bar_sync();                                       // barrier #65
    } else {
        // ================= CONSUMER: layer 2 (s2 chain) =================
        bf16x8 A3a[3], A4[3][2];
#pragma unroll
        for (int t = 0; t < 3; ++t) {
            const int m = 16 * t + j15;
            FragU f3, f4a, f4b;
#pragma unroll
            for (int j = 0; j < 8; ++j) {
                const int k = 8 * g + j;                 // 0..31
                const float v3 = (k < U1) ? g1[k] * W2[k * U2 + m] : 0.f;
                const int kb = 32 + k;                   // 32..63
                const float va = Wr2[k * U2 + m];
                const float vb = (kb < U2) ? Wr2[kb * U2 + m] : (kb == U2 ? br2[m] : 0.f);
                f3.v[j] = (short)f2bf(v3);
                f4a.v[j] = (short)f2bf(va);
                f4b.v[j] = (short)f2bf(vb);
            }
            A3a[t] = f3.v; A4[t][0] = f4a.v; A4[t][1] = f4b.v;
        }
        // per-lane LN-fold constants: c[m] = sum_k bf16(g1.W2), d[m] = b2 + W2^T.be1
        float cC[12], dC[12];
#pragma unroll
        for (int i = 0; i < 12; ++i) {
            const int m = 16 * (i >> 2) + 4 * g + (i & 3);
            float cc = 0.f, dd = b2[m];
            for (int k = 0; k < U1; ++k) {
                cc += bfr(g1[k] * W2[k * U2 + m]);       // match matmul quantization
                dd += be1[k] * W2[k * U2 + m];
            }
            cC[i] = cc; dC[i] = dd;
        }
        f32x4 s2[3] = {z4, z4, z4};

        auto cstep = [&](int t) {
            const unsigned char* sb = ring + (size_t)(t & (SLOTS - 1)) * SLOT_B;
            const bf16x8 hf0 = *(const bf16x8*)(sb + (size_t)j15 * ROWB + 16 * g);
            const float2 ms = *(const float2*)(sb + SUMS_OFF + 8 * j15);

            // GEMM3 P-tiles (gamma-folded W2^T . n1^T)
            const f32x4 P0 = MFMA(A3a[0], hf0, z4);
            const f32x4 P1 = MFMA(A3a[1], hf0, z4);
            const f32x4 P2 = MFMA(A3a[2], hf0, z4);
            const float mu = ms.x, rs = ms.y;

            // y = rs*(P - mu*c) + (d + s2)
            float y[12];
#pragma unroll
            for (int r = 0; r < 4; ++r) {
                y[r]     = fmaf(rs, fmaf(-mu, cC[r],     P0[r]), dC[r]     + s2[0][r]);
                y[4 + r] = fmaf(rs, fmaf(-mu, cC[4 + r], P1[r]), dC[4 + r] + s2[1][r]);
                y[8 + r] = fmaf(rs, fmaf(-mu, cC[8 + r], P2[r]), dC[8 + r] + s2[2][r]);
            }

            // C-layout -> B-frags via bpermute exchange (bias row 48 = inline const)
            const unsigned py00 = pk2(y[0], y[1]),  py01 = pk2(y[2], y[3]);
            const unsigned py10 = pk2(y[4], y[5]),  py11 = pk2(y[6], y[7]);
            const unsigned py20 = pk2(y[8], y[9]),  py21 = pk2(y[10], y[11]);
            const unsigned r00 = bpermu(aA, py00), r01 = bpermu(aA, py01);
            const unsigned r02 = bpermu(aB, py00), r03 = bpermu(aB, py01);
            const unsigned r10 = bpermu(aA, py10), r11 = bpermu(aA, py11);
            const unsigned r12 = bpermu(aB, py10), r13 = bpermu(aB, py11);
            const unsigned q0  = bpermu(aA, py20), q1  = bpermu(aA, py21);
            const unsigned q2  = bpermu(aB, py20), q3  = bpermu(aB, py21);
            FragU yf0, yf1;
            yf0.u[0] = lo ? r00 : r10;
            yf0.u[1] = lo ? r01 : r11;
            yf0.u[2] = lo ? r02 : r12;
            yf0.u[3] = lo ? r03 : r13;
            yf1.u[0] = lo ? q0 : (g == 2 ? 0x00003F80u : 0u);   // row 48 = 1.0 (br2 fold)
            yf1.u[1] = lo ? q1 : 0u;
            yf1.u[2] = lo ? q2 : 0u;
            yf1.u[3] = lo ? q3 : 0u;

            // GEMM4: s2 = tanh([Wr2^T|br2].y^T)
#pragma unroll
            for (int t3 = 0; t3 < 3; ++t3) {
                f32x4 e = MFMA(A4[t3][0], yf0.v, z4);
                e = MFMA(A4[t3][1], yf1.v, e);
#pragma unroll
                for (int r = 0; r < 4; ++r) s2[t3][r] = fast_tanh(e[r]);
            }
        };

        bar_sync();                                       // wait for producer macro 0
#pragma unroll 1
        for (int j = 0; j < 64; ++j) {
#pragma unroll
            for (int i = 0; i < 4; ++i) cstep(4 * j + i);
            bar_sync();                                   // 64 in-loop barriers
        }

        // ---- epilogue: out = sigmoid(LN(s2) @ Wout + bout) ----
        float g2r[12], be2r[12], wor[12];
#pragma unroll
        for (int r = 0; r < 12; ++r) {
            const int n = 16 * (r >> 2) + 4 * g + (r & 3);
            g2r[r] = g2[n]; be2r[r] = be2[n]; wor[r] = Wout[n];
        }
        float sm = 0.f, sq = 0.f;
#pragma unroll
        for (int tt = 0; tt < 3; ++tt)
#pragma unroll
            for (int r = 0; r < 4; ++r) { const float v = s2[tt][r]; sm += v; sq += v * v; }
        sm += __shfl_xor(sm, 16, 64); sq += __shfl_xor(sq, 16, 64);
        sm += __shfl_xor(sm, 32, 64); sq += __shfl_xor(sq, 32, 64);
        const float mu = sm * (1.f / U2);
        const float var = sq * (1.f / U2) - mu * mu;
        const float rs = rsqrtf(var + 1e-3f);
        float p = 0.f;
#pragma unroll
        for (int tt = 0; tt < 3; ++tt)
#pragma unroll
            for (int r = 0; r < 4; ++r)
                p += ((s2[tt][r] - mu) * rs * g2r[4 * tt + r] + be2r[4 * tt + r]) * wor[4 * tt + r];
        p += __shfl_xor(p, 16, 64);
        p += __shfl_xor(p, 32, 64);
        if (lane < 16) {
            const float z = p + bout[0];
            out[blockIdx.x * 16 + lane] = 1.0f / (1.0f + __expf(-z));
        }
    }
}

extern "C" void kernel_launch(void* const* d_in, const int* in_sizes, int n_in,
                              void* d_out, int out_size, void* d_ws, size_t ws_size,
                              hipStream_t stream) {
    const float* seq  = (const float*)d_in[0];
    const float* W1   = (const float*)d_in[1];
    const float* b1   = (const float*)d_in[2];
    const float* Wr1  = (const float*)d_in[3];
    const float* br1  = (const float*)d_in[4];
    const float* g1   = (const float*)d_in[5];
    const float* be1  = (const float*)d_in[6];
    const float* W2   = (const float*)d_in[7];
    const float* b2   = (const float*)d_in[8];
    const float* Wr2  = (const float*)d_in[9];
    const float* br2  = (const float*)d_in[10];
    const float* g2   = (const float*)d_in[11];
    const float* be2  = (const float*)d_in[12];
    const float* Wout = (const float*)d_in[13];
    const float* bout = (const float*)d_in[14];
    float* out = (float*)d_out;

    const int B = in_sizes[0] / (T_STEPS * FEAT);   // 8192
    const int grid = B / 16;                        // 512 blocks x 2 waves
    rnn_kernel<<<grid, 128, 0, stream>>>(seq, W1, b1, Wr1, br1, g1, be1,
                                         W2, b2, Wr2, br2, g2, be2, Wout, bout, out);
}

// Round 7
// 378.708 us; speedup vs baseline: 1.2707x; 1.2707x over previous
//
#include <hip/hip_runtime.h>

#define T_STEPS 256
#define FEAT 16
#define U1 24
#define U2 48
#define SLOTS 8
#define ROWB 144                       // ring/tr row stride (empirically OK conflicts)
#define SLOT_B (16 * ROWB + 128)       // 16 rows + 16 x float2 (rs, rs*mu)
#define SUMS_OFF (16 * ROWB)

typedef short bf16x8 __attribute__((ext_vector_type(8)));
typedef float f32x4 __attribute__((ext_vector_type(4)));

__device__ __forceinline__ unsigned short f2bf(float f) {
    unsigned u = __float_as_uint(f);
    u += 0x7fffu + ((u >> 16) & 1u);   // RNE
    return (unsigned short)(u >> 16);
}

#if defined(__has_builtin)
#if __has_builtin(__builtin_amdgcn_cvt_pk_bf16_f32)
#define HAVE_PKBF16 1
#endif
#endif

__device__ __forceinline__ unsigned pk2(float a, float b) {
#ifdef HAVE_PKBF16
    typedef __bf16 bf2 __attribute__((ext_vector_type(2)));
    union { bf2 v; unsigned u; } cv;
    cv.v = __builtin_amdgcn_cvt_pk_bf16_f32(a, b);       // lo = a, hi = b, RNE
    return cv.u;
#else
    unsigned ua = __float_as_uint(a), ub = __float_as_uint(b);
    ua += 0x7fffu + ((ua >> 16) & 1u);
    ub += 0x7fffu + ((ub >> 16) & 1u);
    return __builtin_amdgcn_perm(ub, ua, 0x07060302);    // [b.hi16 | a.hi16]
#endif
}
__device__ __forceinline__ float fast_tanh(float z) {
    return 1.0f - 2.0f / (1.0f + __expf(2.0f * z));      // robust at +/-inf
}

union FragU { bf16x8 v; unsigned u[4]; };

#define MFMA(A, B, C) __builtin_amdgcn_mfma_f32_16x16x32_bf16((A), (B), (C), 0, 0, 0)

// lgkm-only barrier (0xC07F = vmcnt(63) expcnt(7) lgkmcnt(0)):
// input-prefetch global loads stay in flight across the barrier.
__device__ __forceinline__ void bar_sync() {
    asm volatile("" ::: "memory");
    __builtin_amdgcn_s_waitcnt(0xC07F);
    __builtin_amdgcn_s_barrier();
    asm volatile("" ::: "memory");
}

__global__ __launch_bounds__(128) void rnn_kernel(
    const float* __restrict__ seq,
    const float* __restrict__ W1, const float* __restrict__ b1,
    const float* __restrict__ Wr1, const float* __restrict__ br1,
    const float* __restrict__ g1, const float* __restrict__ be1,
    const float* __restrict__ W2, const float* __restrict__ b2,
    const float* __restrict__ Wr2, const float* __restrict__ br2,
    const float* __restrict__ g2, const float* __restrict__ be2,
    const float* __restrict__ Wout, const float* __restrict__ bout,
    float* __restrict__ out)
{
    __shared__ __align__(16) unsigned char ring[SLOTS * SLOT_B];   // n1 rows + (rs,rs*mu)
    __shared__ __align__(16) unsigned char tr1[16 * ROWB];         // consumer s2 RT rows

    const int tid = threadIdx.x;
    const int w = tid >> 6;              // 0 = layer-1 producer, 1 = layer-2 consumer
    const int lane = tid & 63;
    const int j15 = lane & 15;
    const int g = lane >> 4;
    const f32x4 z4 = {0.f, 0.f, 0.f, 0.f};
    FragU zf; zf.u[0] = zf.u[1] = zf.u[2] = zf.u[3] = 0u;

    if (w == 0) {
        // ============ PRODUCER: layer 1, chain = {MFMA, tanh, RT} ============
        // A1f = ([W1;b1] . Wr1)^T folded input weights (K = 17 -> frame 32)
        bf16x8 A1f[2], A2[2];
        f32x4 Cb1[2];
#pragma unroll
        for (int t = 0; t < 2; ++t) {
            const int m = 16 * t + j15;
            FragU f1, f2;
#pragma unroll
            for (int j = 0; j < 8; ++j) {
                const int k = 8 * g + j;
                float v1 = 0.f;
                if (m < U1 && k <= FEAT) {
                    for (int u = 0; u < U1; ++u) {
                        const float w1e = (k < FEAT) ? W1[k * U1 + u] : b1[u];
                        v1 = fmaf(w1e, Wr1[u * U1 + m], v1);
                    }
                }
                f1.v[j] = (short)f2bf(v1);
                f2.v[j] = (m < U1 && k < U1) ? (short)f2bf(Wr1[k * U1 + m]) : (short)0;
            }
            A1f[t] = f1.v; A2[t] = f2.v;
            f32x4 cb;
#pragma unroll
            for (int r = 0; r < 4; ++r) {
                const int mm = 16 * t + 4 * g + r;
                cb[r] = (mm < U1) ? br1[mm] : 0.f;
            }
            Cb1[t] = cb;
        }
        const unsigned cdw0 = (g == 2) ? 0x00003F80u : 0u;   // input k16 = 1.0
        const bool lo = (g < 2);

        const float* sp = seq + (size_t)(blockIdx.x * 16 + j15) * (T_STEPS * FEAT) + 8 * g;
        const bool ld = (lane < 32);

        float4 ca[4], cb4[4], na[4], nb[4];
        if (ld) {
#pragma unroll
            for (int i = 0; i < 4; ++i) {
                ca[i] = *(const float4*)(sp + i * 16);
                cb4[i] = *(const float4*)(sp + i * 16 + 4);
            }
        }

        bf16x8 s1f = zf.v;                                   // s1(t=-1) = 0

#pragma unroll 1
        for (int j = 0; j < 64; ++j) {
            const int jn = (j + 1 < 64) ? j + 1 : j;         // prefetch next macro
            if (ld) {
#pragma unroll
                for (int i = 0; i < 4; ++i) {
                    na[i] = *(const float4*)(sp + (4 * jn + i) * 16);
                    nb[i] = *(const float4*)(sp + (4 * jn + i) * 16 + 4);
                }
            }
            // ---- off-chain: Pin = [W1;b1]Wr1)^T . in_ext + br1 for 4 steps ----
            f32x4 PinA[4], PinB[4];
#pragma unroll
            for (int i = 0; i < 4; ++i) {
                FragU inf;
                const unsigned p0 = pk2(ca[i].x, ca[i].y), p1 = pk2(ca[i].z, ca[i].w);
                const unsigned p2 = pk2(cb4[i].x, cb4[i].y), p3 = pk2(cb4[i].z, cb4[i].w);
                inf.u[0] = lo ? p0 : cdw0;
                inf.u[1] = lo ? p1 : 0u;
                inf.u[2] = lo ? p2 : 0u;
                inf.u[3] = lo ? p3 : 0u;
                PinA[i] = MFMA(A1f[0], inf.v, Cb1[0]);
                PinB[i] = MFMA(A1f[1], inf.v, Cb1[1]);
            }
            // ---- chain: 4 steps ----
#pragma unroll
            for (int i = 0; i < 4; ++i) {
                const int t = 4 * j + i;
                const f32x4 a0 = MFMA(A2[0], s1f, PinA[i]);
                const f32x4 a1 = MFMA(A2[1], s1f, PinB[i]);
                float n1a[4], n1b[4];
#pragma unroll
                for (int r = 0; r < 4; ++r) { n1a[r] = fast_tanh(a0[r]); n1b[r] = fast_tanh(a1[r]); }

                unsigned char* rp = ring + (size_t)(t & (SLOTS - 1)) * SLOT_B + (size_t)j15 * ROWB;
                *(uint2*)(rp + 8 * g)      = make_uint2(pk2(n1a[0], n1a[1]), pk2(n1a[2], n1a[3]));
                *(uint2*)(rp + 32 + 8 * g) = make_uint2(pk2(n1b[0], n1b[1]), pk2(n1b[2], n1b[3]));
                // read back own B-frag for next step (in-order DS within wave)
                s1f = *(const bf16x8*)(rp - (size_t)j15 * ROWB + (size_t)j15 * ROWB + 16 * g);

                // off-chain stats -> (rs, rs*mu)
                float sm = 0.f, sq = 0.f;
#pragma unroll
                for (int r = 0; r < 4; ++r) {
                    sm += n1a[r] + n1b[r];
                    sq = fmaf(n1a[r], n1a[r], sq);
                    sq = fmaf(n1b[r], n1b[r], sq);
                }
                sm += __shfl_xor(sm, 16, 64); sq += __shfl_xor(sq, 16, 64);
                sm += __shfl_xor(sm, 32, 64); sq += __shfl_xor(sq, 32, 64);
                const float mu = sm * (1.f / U1);
                const float rs = rsqrtf(sq * (1.f / U1) - mu * mu + 1e-3f);
                if (lane < 16)
                    *(float2*)(ring + (size_t)(t & (SLOTS - 1)) * SLOT_B + SUMS_OFF + 8 * j15) =
                        make_float2(rs, rs * mu);
            }
            bar_sync();
#pragma unroll
            for (int i = 0; i < 4; ++i) { ca[i] = na[i]; cb4[i] = nb[i]; }
        }
        bar_sync();                                          // barrier #65
    } else {
        // ============ CONSUMER: layer 2, chain = {MFMA, tanh, RT} ============
        // zero tr1 (esp. bytes 96..127 = k48..63 pads, never rewritten)
        for (int i = lane; i < 16 * ROWB / 4; i += 64) ((unsigned*)tr1)[i] = 0u;

        // A_Q = ((g1 . W2) Wr2)^T (K = 24 -> 32); A4 = Wr2^T (K = 48 -> 64)
        bf16x8 AQ[3], A4[3][2];
#pragma unroll
        for (int t = 0; t < 3; ++t) {
            const int m = 16 * t + j15;
            FragU fq, f4a, f4b;
#pragma unroll
            for (int j = 0; j < 8; ++j) {
                const int k = 8 * g + j;                     // 0..31
                float vq = 0.f;
                if (k < U1) {
                    float s = 0.f;
                    for (int u = 0; u < U2; ++u) s = fmaf(W2[k * U2 + u], Wr2[u * U2 + m], s);
                    vq = g1[k] * s;
                }
                const int kb = 32 + k;                       // 32..63
                f4a.v[j] = (short)f2bf(Wr2[k * U2 + m]);
                f4b.v[j] = (kb < U2) ? (short)f2bf(Wr2[kb * U2 + m]) : (short)0;
                fq.v[j] = (short)f2bf(vq);
            }
            AQ[t] = fq.v; A4[t][0] = f4a.v; A4[t][1] = f4b.v;
        }
        // c[u] = sum_k g1[k]W2[k,u]; d[u] = b2[u] + sum_k be1[k]W2[k,u]
        // q1C[m] = Wr2^T c; q2C[m] = Wr2^T d + br2
        float q1C[12], q2C[12];
        {
            float cv[U2], dv[U2];
            for (int u = 0; u < U2; ++u) {
                float cc = 0.f, dd = b2[u];
                for (int k = 0; k < U1; ++k) {
                    const float w2 = W2[k * U2 + u];
                    cc = fmaf(g1[k], w2, cc);
                    dd = fmaf(be1[k], w2, dd);
                }
                cv[u] = cc; dv[u] = dd;
            }
#pragma unroll
            for (int i = 0; i < 12; ++i) {
                const int m = 16 * (i >> 2) + 4 * g + (i & 3);
                float a1 = 0.f, a2 = br2[m];
                for (int u = 0; u < U2; ++u) {
                    const float wr = Wr2[u * U2 + m];
                    a1 = fmaf(cv[u], wr, a1);
                    a2 = fmaf(dv[u], wr, a2);
                }
                q1C[i] = a1; q2C[i] = a2;
            }
        }
        unsigned char* const yrow = tr1 + (size_t)j15 * ROWB;
        f32x4 s2c[3] = {z4, z4, z4};
        bf16x8 s2f0 = zf.v, s2f1 = zf.v;

        bar_sync();                                          // producer macro 0 done
#pragma unroll 1
        for (int j = 0; j < 64; ++j) {
            // ---- off-chain: E = rs*Q + (q2 - rs*mu*q1) for the macro's 4 steps ----
            f32x4 E[4][3];
#pragma unroll
            for (int i = 0; i < 4; ++i) {
                const int t = 4 * j + i;
                const unsigned char* sb = ring + (size_t)(t & (SLOTS - 1)) * SLOT_B;
                const bf16x8 nf = *(const bf16x8*)(sb + (size_t)j15 * ROWB + 16 * g);
                const float2 ms = *(const float2*)(sb + SUMS_OFF + 8 * j15);   // (rs, rs*mu)
                const f32x4 Q0 = MFMA(AQ[0], nf, z4);
                const f32x4 Q1 = MFMA(AQ[1], nf, z4);
                const f32x4 Q2 = MFMA(AQ[2], nf, z4);
#pragma unroll
                for (int r = 0; r < 4; ++r) {
                    E[i][0][r] = fmaf(ms.x, Q0[r], fmaf(-ms.y, q1C[r],     q2C[r]));
                    E[i][1][r] = fmaf(ms.x, Q1[r], fmaf(-ms.y, q1C[4 + r], q2C[4 + r]));
                    E[i][2][r] = fmaf(ms.x, Q2[r], fmaf(-ms.y, q1C[8 + r], q2C[8 + r]));
                }
            }
            // ---- chain: 4 steps ----
#pragma unroll
            for (int i = 0; i < 4; ++i) {
                f32x4 e0 = MFMA(A4[0][0], s2f0, E[i][0]);
                f32x4 e1 = MFMA(A4[1][0], s2f0, E[i][1]);
                f32x4 e2 = MFMA(A4[2][0], s2f0, E[i][2]);
                e0 = MFMA(A4[0][1], s2f1, e0);
                e1 = MFMA(A4[1][1], s2f1, e1);
                e2 = MFMA(A4[2][1], s2f1, e2);
#pragma unroll
                for (int r = 0; r < 4; ++r) {
                    s2c[0][r] = fast_tanh(e0[r]);
                    s2c[1][r] = fast_tanh(e1[r]);
                    s2c[2][r] = fast_tanh(e2[r]);
                }
                *(uint2*)(yrow + 8 * g)      = make_uint2(pk2(s2c[0][0], s2c[0][1]), pk2(s2c[0][2], s2c[0][3]));
                *(uint2*)(yrow + 32 + 8 * g) = make_uint2(pk2(s2c[1][0], s2c[1][1]), pk2(s2c[1][2], s2c[1][3]));
                *(uint2*)(yrow + 64 + 8 * g) = make_uint2(pk2(s2c[2][0], s2c[2][1]), pk2(s2c[2][2], s2c[2][3]));
                s2f0 = *(const bf16x8*)(tr1 + (size_t)j15 * ROWB + 16 * g);
                s2f1 = *(const bf16x8*)(tr1 + (size_t)j15 * ROWB + 64 + 16 * g);
            }
            bar_sync();
        }

        // ---- epilogue: out = sigmoid(LN(s2) @ Wout + bout) ----
        float g2r[12], be2r[12], wor[12];
#pragma unroll
        for (int r = 0; r < 12; ++r) {
            const int n = 16 * (r >> 2) + 4 * g + (r & 3);
            g2r[r] = g2[n]; be2r[r] = be2[n]; wor[r] = Wout[n];
        }
        float sm = 0.f, sq = 0.f;
#pragma unroll
        for (int tt = 0; tt < 3; ++tt)
#pragma unroll
            for (int r = 0; r < 4; ++r) { const float v = s2c[tt][r]; sm += v; sq += v * v; }
        sm += __shfl_xor(sm, 16, 64); sq += __shfl_xor(sq, 16, 64);
        sm += __shfl_xor(sm, 32, 64); sq += __shfl_xor(sq, 32, 64);
        const float mu = sm * (1.f / U2);
        const float var = sq * (1.f / U2) - mu * mu;
        const float rs = rsqrtf(var + 1e-3f);
        float p = 0.f;
#pragma unroll
        for (int tt = 0; tt < 3; ++tt)
#pragma unroll
            for (int r = 0; r < 4; ++r)
                p += ((s2c[tt][r] - mu) * rs * g2r[4 * tt + r] + be2r[4 * tt + r]) * wor[4 * tt + r];
        p += __shfl_xor(p, 16, 64);
        p += __shfl_xor(p, 32, 64);
        if (lane < 16) {
            const float z = p + bout[0];
            out[blockIdx.x * 16 + lane] = 1.0f / (1.0f + __expf(-z));
        }
    }
}

extern "C" void kernel_launch(void* const* d_in, const int* in_sizes, int n_in,
                              void* d_out, int out_size, void* d_ws, size_t ws_size,
                              hipStream_t stream) {
    const float* seq  = (const float*)d_in[0];
    const float* W1   = (const float*)d_in[1];
    const float* b1   = (const float*)d_in[2];
    const float* Wr1  = (const float*)d_in[3];
    const float* br1  = (const float*)d_in[4];
    const float* g1   = (const float*)d_in[5];
    const float* be1  = (const float*)d_in[6];
    const float* W2   = (const float*)d_in[7];
    const float* b2   = (const float*)d_in[8];
    const float* Wr2  = (const float*)d_in[9];
    const float* br2  = (const float*)d_in[10];
    const float* g2   = (const float*)d_in[11];
    const float* be2  = (const float*)d_in[12];
    const float* Wout = (const float*)d_in[13];
    const float* bout = (const float*)d_in[14];
    float* out = (float*)d_out;

    const int B = in_sizes[0] / (T_STEPS * FEAT);   // 8192
    const int grid = B / 16;                        // 512 blocks x 2 waves
    rnn_kernel<<<grid, 128, 0, stream>>>(seq, W1, b1, Wr1, br1, g1, be1,
                                         W2, b2, Wr2, br2, g2, be2, Wout, bout, out);
}